// Round 1
// baseline (35468.262 us; speedup 1.0000x reference)
//
#include <hip/hip_runtime.h>

// Problem constants: B=64, T=512, IN=256, H=1024, L=2, OUT=128
#define B_ 64
#define T_ 512
#define IN_ 256
#define H_ 1024
#define OUT_ 128
#define NBLK 256

// ---------------------------------------------------------------------------
// Grid barrier for a co-resident (cooperative) launch.
// Release fence (wbL2) before arrival makes h-writes visible at the MALL;
// acquire fence (buffer_inv) after release makes every CU's L1/L2 drop stale
// copies of re-read buffers (h1 ping-pong, ys rows). Weights live in LDS, so
// the per-step L2 invalidation costs ~nothing.
// ---------------------------------------------------------------------------
__device__ __forceinline__ void grid_barrier(unsigned* bar, unsigned nblk) {
  __syncthreads();
  if (threadIdx.x == 0) {
    __builtin_amdgcn_fence(__ATOMIC_RELEASE, "agent");
    unsigned g = __hip_atomic_load(bar + 1, __ATOMIC_RELAXED, __HIP_MEMORY_SCOPE_AGENT);
    unsigned arrived =
        __hip_atomic_fetch_add(bar, 1u, __ATOMIC_RELAXED, __HIP_MEMORY_SCOPE_AGENT) + 1u;
    if (arrived == nblk) {
      __hip_atomic_store(bar, 0u, __ATOMIC_RELAXED, __HIP_MEMORY_SCOPE_AGENT);
      __hip_atomic_fetch_add(bar + 1, 1u, __ATOMIC_RELEASE, __HIP_MEMORY_SCOPE_AGENT);
    } else {
      while (__hip_atomic_load(bar + 1, __ATOMIC_RELAXED, __HIP_MEMORY_SCOPE_AGENT) == g) {
        __builtin_amdgcn_s_sleep(1);
      }
    }
    __builtin_amdgcn_fence(__ATOMIC_ACQUIRE, "agent");
  }
  __syncthreads();
}

// dot of 1024 floats: g = global row (16B aligned), l = (LDS) weight row with
// XOR swizzle sw applied to the float index (sw = 0 for plain rows).
__device__ __forceinline__ float dot1024(const float* __restrict__ g,
                                         const float* __restrict__ l, int sw) {
  float s0 = 0.f, s1 = 0.f, s2 = 0.f, s3 = 0.f;
#pragma unroll 2
  for (int k = 0; k < 1024; k += 16) {
    float4 a0 = *(const float4*)(g + k + 0);
    float4 a1 = *(const float4*)(g + k + 4);
    float4 a2 = *(const float4*)(g + k + 8);
    float4 a3 = *(const float4*)(g + k + 12);
    float4 w0 = *(const float4*)(l + ((k + 0) ^ sw));
    float4 w1 = *(const float4*)(l + ((k + 4) ^ sw));
    float4 w2 = *(const float4*)(l + ((k + 8) ^ sw));
    float4 w3 = *(const float4*)(l + ((k + 12) ^ sw));
    s0 += a0.x * w0.x + a0.y * w0.y + a0.z * w0.z + a0.w * w0.w;
    s1 += a1.x * w1.x + a1.y * w1.y + a1.z * w1.z + a1.w * w1.w;
    s2 += a2.x * w2.x + a2.y * w2.y + a2.z * w2.z + a2.w * w2.w;
    s3 += a3.x * w3.x + a3.y * w3.y + a3.z * w3.z + a3.w * w3.w;
  }
  return (s0 + s1) + (s2 + s3);
}

// ---------------------------------------------------------------------------
// Kernel 1: xw0[t][b][:] = x[b][t][:] @ W_ih0^T + (b_ih0 + b_hh0)
// M = T*B = 32768 (row r = t*64 + b), N = 1024, K = 256. Plain fp32 tile GEMM.
// grid: (16 col-tiles, 512 t), block 256, 64x64 tile, 4x4 per thread.
// ---------------------------------------------------------------------------
__global__ __launch_bounds__(256) void xw0_gemm(const float* __restrict__ x,
                                                const float* __restrict__ W,
                                                const float* __restrict__ bih,
                                                const float* __restrict__ bhh,
                                                float* __restrict__ xw) {
  __shared__ float As[64][65];
  __shared__ float Bs[64][65];
  const int t = blockIdx.y;
  const int j0 = blockIdx.x * 64;
  const int tid = threadIdx.x;
  const int tb = (tid & 15) * 4;  // A-row (b) base for compute
  const int tj = (tid >> 4) * 4;  // B-row (j) base for compute
  float acc[4][4] = {};

  for (int kt = 0; kt < 256; kt += 64) {
    const int lr = tid >> 4;          // 0..15 load row
    const int kq = (tid & 15) * 4;    // 0..60 load col (float4)
#pragma unroll
    for (int p = 0; p < 4; ++p) {
      int r = lr + p * 16;  // 0..63
      float4 va = *(const float4*)(x + (r * T_ + t) * IN_ + kt + kq);
      As[r][kq + 0] = va.x; As[r][kq + 1] = va.y;
      As[r][kq + 2] = va.z; As[r][kq + 3] = va.w;
      float4 vb = *(const float4*)(W + (j0 + r) * IN_ + kt + kq);
      Bs[r][kq + 0] = vb.x; Bs[r][kq + 1] = vb.y;
      Bs[r][kq + 2] = vb.z; Bs[r][kq + 3] = vb.w;
    }
    __syncthreads();
#pragma unroll 4
    for (int k = 0; k < 64; ++k) {
      float a0 = As[tb + 0][k], a1 = As[tb + 1][k], a2 = As[tb + 2][k], a3 = As[tb + 3][k];
      float b0 = Bs[tj + 0][k], b1 = Bs[tj + 1][k], b2 = Bs[tj + 2][k], b3 = Bs[tj + 3][k];
      acc[0][0] += a0 * b0; acc[0][1] += a0 * b1; acc[0][2] += a0 * b2; acc[0][3] += a0 * b3;
      acc[1][0] += a1 * b0; acc[1][1] += a1 * b1; acc[1][2] += a1 * b2; acc[1][3] += a1 * b3;
      acc[2][0] += a2 * b0; acc[2][1] += a2 * b1; acc[2][2] += a2 * b2; acc[2][3] += a2 * b3;
      acc[3][0] += a3 * b0; acc[3][1] += a3 * b1; acc[3][2] += a3 * b2; acc[3][3] += a3 * b3;
    }
    __syncthreads();
  }

  const int row0 = t * B_;
#pragma unroll
  for (int i = 0; i < 4; ++i) {
    int b = tb + i;
#pragma unroll
    for (int jj = 0; jj < 4; ++jj) {
      int col = j0 + tj + jj;
      acc[i][jj] += bih[col] + bhh[col];
    }
    float4 v = make_float4(acc[i][0], acc[i][1], acc[i][2], acc[i][3]);
    *(float4*)(xw + (row0 + b) * H_ + j0 + tj) = v;
  }
}

// ---------------------------------------------------------------------------
// Kernel 2: persistent cooperative kernel.
//   phase 0: stage W_hh0 16-row slice into LDS; ys[0] = tanh(xw0[0])
//   layer 0: t = 1..511: ys[t] = tanh(xw0[t] + ys[t-1] @ W_hh0^T)   (in place)
//   restage: [W_ih1 | W_hh1] 16-row slice into LDS (128 KiB dynamic)
//   layer 1: t = 0..511: h1 = tanh(b1 + ys[t]@W_ih1^T + h1prev@W_hh1^T)
//            ping-pong h1a/h1b (t even -> h1a, odd -> h1b; t=511 -> h1b)
//   final:   out = sigmoid([ys[511], h1b] @ W_lin^T + b_lin)
// grid 256 blocks x 256 threads, 1 block/CU. Block owns 16 b x 16 j outputs.
// ---------------------------------------------------------------------------
__global__ __launch_bounds__(256, 1) void rnn_seq(
    const float* __restrict__ Whh0, const float* __restrict__ Wih1,
    const float* __restrict__ Whh1, const float* __restrict__ bih1,
    const float* __restrict__ bhh1, const float* __restrict__ Wlin,
    const float* __restrict__ blin, float* __restrict__ ys, float* __restrict__ h1a,
    float* __restrict__ h1b, unsigned* __restrict__ bar, float* __restrict__ out) {
  extern __shared__ float lds[];  // 16*2048 floats = 128 KiB
  const int tid = threadIdx.x;
  const int blk = blockIdx.x;
  // XCD-aware decomposition: blocks on one XCD share 8 consecutive j-groups,
  // so each XCD's L2 only streams its own h rows within a step.
  const int xcd = blk & 7;
  const int idx = blk >> 3;
  const int jg = xcd * 8 + (idx & 7);  // 0..63 -> 16 output columns
  const int bg = idx >> 3;             // 0..3  -> 16 batch rows
  const int jl = tid & 15;
  const int bl = tid >> 4;
  const int b = bg * 16 + bl;
  const int j = jg * 16 + jl;
  const int sw = (jl & 7) << 2;  // LDS XOR swizzle for this thread's W row

  // ---- phase 0: stage Whh0 slice (16 x 1024), tanh on ys[0]
  for (int i4 = tid * 4; i4 < 16 * 1024; i4 += 256 * 4) {
    int r = i4 >> 10, k = i4 & 1023;
    float4 v = *(const float4*)(Whh0 + (jg * 16 + r) * H_ + k);
    *(float4*)(lds + r * 1024 + (k ^ ((r & 7) << 2))) = v;
  }
  {
    int i = blk * 256 + tid;  // exactly covers 64*1024
    ys[i] = tanhf(ys[i]);
  }
  grid_barrier(bar, NBLK);

  // ---- layer 0 recurrence (in place over ys)
  const float* wl0 = lds + jl * 1024;
  for (int t = 1; t < T_; ++t) {
    const float* hrow = ys + ((t - 1) * B_ + b) * H_;
    float acc = ys[(t * B_ + b) * H_ + j];
    acc += dot1024(hrow, wl0, sw);
    ys[(t * B_ + b) * H_ + j] = tanhf(acc);
    grid_barrier(bar, NBLK);
  }

  // ---- restage LDS with [W_ih1 | W_hh1] slice (16 x 2048)
  for (int i4 = tid * 4; i4 < 16 * 2048; i4 += 256 * 4) {
    int r = i4 >> 11, k = i4 & 2047;
    float4 v;
    if (k < 1024)
      v = *(const float4*)(Wih1 + (jg * 16 + r) * H_ + k);
    else
      v = *(const float4*)(Whh1 + (jg * 16 + r) * H_ + (k - 1024));
    *(float4*)(lds + r * 2048 + (k ^ ((r & 7) << 2))) = v;
  }
  __syncthreads();

  // ---- layer 1 recurrence (K = 2048 fused), h1 ping-pong
  const float* wi1 = lds + jl * 2048;
  const float* wh1 = wi1 + 1024;
  const float bs1 = bih1[j] + bhh1[j];
  for (int t = 0; t < T_; ++t) {
    const float* xrow = ys + (t * B_ + b) * H_;
    float acc = bs1 + dot1024(xrow, wi1, sw);
    if (t > 0) {
      const float* hr = ((t & 1) ? h1a : h1b) + b * H_;
      acc += dot1024(hr, wh1, sw);
    }
    float* hw = (t & 1) ? h1b : h1a;
    hw[b * H_ + j] = tanhf(acc);
    grid_barrier(bar, NBLK);
  }

  // ---- final linear + sigmoid: out[64][128]
  if (blk < 32) {
    const int o = tid & 127;
    const int bb = blk * 2 + (tid >> 7);
    const float* wrow = Wlin + o * (2 * H_);
    float acc = blin[o];
    acc += dot1024(ys + ((T_ - 1) * B_ + bb) * H_, wrow, 0);
    acc += dot1024(h1b + bb * H_, wrow + 1024, 0);
    out[bb * OUT_ + o] = 1.0f / (1.0f + expf(-acc));
  }
}

// ---------------------------------------------------------------------------
extern "C" void kernel_launch(void* const* d_in, const int* in_sizes, int n_in,
                              void* d_out, int out_size, void* d_ws, size_t ws_size,
                              hipStream_t stream) {
  const float* x    = (const float*)d_in[0];
  const float* Wih0 = (const float*)d_in[1];
  const float* Whh0 = (const float*)d_in[2];
  const float* bih0 = (const float*)d_in[3];
  const float* bhh0 = (const float*)d_in[4];
  const float* Wih1 = (const float*)d_in[5];
  const float* Whh1 = (const float*)d_in[6];
  const float* bih1 = (const float*)d_in[7];
  const float* bhh1 = (const float*)d_in[8];
  const float* Wlin = (const float*)d_in[9];
  const float* blin = (const float*)d_in[10];
  float* out = (float*)d_out;

  char* ws = (char*)d_ws;
  const size_t YS_BYTES = (size_t)T_ * B_ * H_ * 4;  // 128 MiB
  float* ys  = (float*)ws;
  float* h1a = (float*)(ws + YS_BYTES);
  float* h1b = (float*)(ws + YS_BYTES + (size_t)B_ * H_ * 4);
  unsigned* bar = (unsigned*)(ws + YS_BYTES + 2 * (size_t)B_ * H_ * 4);

  hipMemsetAsync(bar, 0, 256, stream);

  xw0_gemm<<<dim3(16, T_), 256, 0, stream>>>(x, Wih0, bih0, bhh0, ys);

  const int dyn_lds = 16 * 2048 * 4;  // 128 KiB
  hipFuncSetAttribute((const void*)rnn_seq, hipFuncAttributeMaxDynamicSharedMemorySize,
                      dyn_lds);
  void* args[] = {&Whh0, &Wih1, &Whh1, &bih1, &bhh1, &Wlin,
                  &blin, &ys,   &h1a,  &h1b,  &bar,  &out};
  hipLaunchCooperativeKernel((const void*)rnn_seq, dim3(NBLK), dim3(256), args, dyn_lds,
                             stream);
}